// Round 8
// baseline (3887.470 us; speedup 1.0000x reference)
//
#include <hip/hip_runtime.h>

#define IN_DIM 50
#define H1 128
#define H2 128
#define HID 256
#define N_Y 100
#define STEPS 100
#define BATCH 16384
#define ROWS 64
#define NTHR 1024

typedef float f32x16 __attribute__((ext_vector_type(16)));
typedef __bf16 bf16x8 __attribute__((ext_vector_type(8)));
typedef int i32x4 __attribute__((ext_vector_type(4)));

// LDS layout (bytes)
#define CSTRIDE 264                 // bf16 cells per row incl. pad -> 528 B rows
#define HHI_OFF 0                   // h_hi [64][264] bf16 = 33792
#define HLO_OFF 33792               // h_lo                 = 33792
#define EXCH_OFF 67584              // [8 cb][2 rt][16 r][64 lane] f32 = 65536
#define SMEM_BYTES 133120
// MLP-time aliases (all dead before the LSTM loop):
#define H1T_OFF 0                   // h1t f32[128][64] = 32768 (inside h_hi/h_lo)
#define XT_OFF  67584               // xt  f32[50][64]  = 12800
#define H2T_OFF 80384               // h2t f32[128][64] = 32768 (ends 113152)

// ws layout (bytes) — unchanged from R2 (verified layout math)
#define WGH_OFF 0                   // Wg_hi frag-major: 32 nt x 16 kt x 1024B
#define WGL_OFF 524288
#define WOH_OFF 1048576             // Wo frag-major: 4 nt x 16 kt x 1024B
#define WOL_OFF 1114112
#define BG_OFF  1179648             // f32[1024]
#define BO_OFF  1183744             // f32[128] padded

__device__ __forceinline__ float fast_sigmoid(float x) {
    float e = __expf(-x);
    return __builtin_amdgcn_rcpf(1.0f + e);
}
__device__ __forceinline__ float fast_tanh(float x) {
    float e = __expf(2.0f * x);
    return 1.0f - 2.0f * __builtin_amdgcn_rcpf(1.0f + e);
}
__device__ __forceinline__ unsigned short bf16bits(float x) {
    __bf16 b = (__bf16)x;
    return __builtin_bit_cast(unsigned short, b);
}
__device__ __forceinline__ float bits2f(unsigned short u) {
    __bf16 b = __builtin_bit_cast(__bf16, u);
    return (float)b;
}
__device__ __forceinline__ f32x16 splat16(float v) {
    f32x16 r;
    #pragma unroll
    for (int i = 0; i < 16; ++i) r[i] = v;
    return r;
}

// ---- prep: split weights to bf16 hi/lo in MFMA-fragment-major order ----
// B-frag (32x32x16): lane l holds B[k = kt*16 + (l>>5)*8 + i][n = nt*32 + (l&31)],
// stored at block (nt*16+kt)*512 + ((n&31) + 32*((k>>3)&1))*8 + (k&7) (bf16 units).
extern "C" __global__ void prep_kernel(const float* __restrict__ Wih,
                                       const float* __restrict__ Whh,
                                       const float* __restrict__ bih,
                                       const float* __restrict__ bhh,
                                       const float* __restrict__ Wo,
                                       const float* __restrict__ bo,
                                       char* __restrict__ ws) {
    int idx = blockIdx.x * blockDim.x + threadIdx.x;
    if (idx < 262144) {                       // Wg = Wih + Whh, [1024][256]
        int n = idx >> 8, k = idx & 255;
        float v = Wih[n * HID + k] + Whh[n * HID + k];
        __bf16 hi = (__bf16)v;
        __bf16 lo = (__bf16)(v - (float)hi);
        int dst = ((n >> 5) * 16 + (k >> 4)) * 512 + ((n & 31) + 32 * ((k >> 3) & 1)) * 8 + (k & 7);
        ((__bf16*)(ws + WGH_OFF))[dst] = hi;
        ((__bf16*)(ws + WGL_OFF))[dst] = lo;
    } else if (idx < 294912) {                // Wo padded to [128][256]
        int j = idx - 262144;
        int n = j >> 8, k = j & 255;
        float v = (n < N_Y) ? Wo[n * HID + k] : 0.0f;
        __bf16 hi = (__bf16)v;
        __bf16 lo = (__bf16)(v - (float)hi);
        int dst = ((n >> 5) * 16 + (k >> 4)) * 512 + ((n & 31) + 32 * ((k >> 3) & 1)) * 8 + (k & 7);
        ((__bf16*)(ws + WOH_OFF))[dst] = hi;
        ((__bf16*)(ws + WOL_OFF))[dst] = lo;
    } else if (idx < 295936) {                // bg
        int n = idx - 294912;
        ((float*)(ws + BG_OFF))[n] = bih[n] + bhh[n];
    } else if (idx < 296064) {                // bo padded
        int n = idx - 295936;
        ((float*)(ws + BO_OFF))[n] = (n < N_Y) ? bo[n] : 0.0f;
    }
}

// 16 waves / 1024 threads, 64 rows per block, 1 block/CU (LDS 130 KiB) -> 4 waves/SIMD.
// Wave roles: w<8 ("lo"): gate tiles i (nt=cb) and g (nt=16+cb); computes p=sig(i)*tanh(g),
// exports p via LDS, and owns the y-projection. w>=8 ("hi"): gate tiles f (nt=8+cb),
// o (nt=24+cb); owns c-state, computes c,h and the h-write. cb = cell block = w&7.
extern "C" __global__ void __launch_bounds__(NTHR, 4)
rnn_main(const float* __restrict__ x,
         const float* __restrict__ W1, const float* __restrict__ b1,
         const float* __restrict__ W2, const float* __restrict__ b2,
         const float* __restrict__ W3, const float* __restrict__ b3,
         const char* __restrict__ ws,
         float* __restrict__ out)
{
    __shared__ __align__(16) char smem[SMEM_BYTES];

    const int tid  = threadIdx.x;
    const int lane = tid & 63;
    const int lm   = lane & 31;
    const int l5   = lane >> 5;
    const int w    = __builtin_amdgcn_readfirstlane(tid >> 6);   // wave 0..15
    const int r0   = blockIdx.x * ROWS;
    const bool isLo = (w < 8);
    const int cb   = w & 7;                  // cell block 0..7
    const int nt0  = (isLo ? 0 : 8) + cb;    // gate i or f
    const int nt1  = nt0 + 16;               // gate g or o

    // ================= MLP prologue (fp32 vector, lane = row) =================
    {
        float* xt  = (float*)(smem + XT_OFF);    // [50][64]
        float* h1t = (float*)(smem + H1T_OFF);   // [128][64]
        float* h2t = (float*)(smem + H2T_OFF);   // [128][64]

        for (int i = tid; i < ROWS * IN_DIM; i += NTHR) {
            int r = i / IN_DIM, k = i - r * IN_DIM;
            xt[k * ROWS + r] = x[(size_t)(r0 + r) * IN_DIM + k];
        }
        __syncthreads();

        // layer 1: 8 neurons per wave
        {
            const int jb = w * 8;
            float acc[8];
            #pragma unroll
            for (int jj = 0; jj < 8; ++jj) acc[jj] = b1[jb + jj];
            for (int k = 0; k < IN_DIM; ++k) {
                float h = xt[k * ROWS + lane];
                #pragma unroll
                for (int jj = 0; jj < 8; ++jj)
                    acc[jj] = fmaf(h, W1[(jb + jj) * IN_DIM + k], acc[jj]);
            }
            #pragma unroll
            for (int jj = 0; jj < 8; ++jj)
                h1t[(jb + jj) * ROWS + lane] = fmaxf(acc[jj], 0.0f);
        }
        __syncthreads();

        // layer 2: 8 neurons per wave
        {
            const int jb = w * 8;
            float acc[8];
            #pragma unroll
            for (int jj = 0; jj < 8; ++jj) acc[jj] = b2[jb + jj];
            for (int k = 0; k < H1; ++k) {
                float h = h1t[k * ROWS + lane];
                #pragma unroll
                for (int jj = 0; jj < 8; ++jj)
                    acc[jj] = fmaf(h, W2[(jb + jj) * H1 + k], acc[jj]);
            }
            #pragma unroll
            for (int jj = 0; jj < 8; ++jj)
                h2t[(jb + jj) * ROWS + lane] = fmaxf(acc[jj], 0.0f);
        }
        __syncthreads();

        // layer 3: 16 cells per wave -> h0 hi/lo bf16 into LDS (row-major)
        unsigned short* hhi = (unsigned short*)(smem + HHI_OFF);
        unsigned short* hlo = (unsigned short*)(smem + HLO_OFF);
        #pragma unroll
        for (int jt = 0; jt < 2; ++jt) {
            const int jb = w * 16 + jt * 8;
            float acc[8];
            #pragma unroll
            for (int jj = 0; jj < 8; ++jj) acc[jj] = b3[jb + jj];
            for (int k = 0; k < H2; ++k) {
                float h = h2t[k * ROWS + lane];
                #pragma unroll
                for (int jj = 0; jj < 8; ++jj)
                    acc[jj] = fmaf(h, W3[(jb + jj) * H2 + k], acc[jj]);
            }
            #pragma unroll
            for (int jj = 0; jj < 8; ++jj) {
                float v = fmaxf(acc[jj], 0.0f);
                unsigned short hb = bf16bits(v);
                unsigned short lb = bf16bits(v - bits2f(hb));
                hhi[lane * CSTRIDE + jb + jj] = hb;
                hlo[lane * CSTRIDE + jb + jj] = lb;
            }
        }
        __syncthreads();
    }

    // ================= LSTM + output projection =================
    const bf16x8* __restrict__ BgH = (const bf16x8*)(ws + WGH_OFF);
    const bf16x8* __restrict__ BgL = (const bf16x8*)(ws + WGL_OFF);
    const bf16x8* __restrict__ BoH = (const bf16x8*)(ws + WOH_OFF);
    const bf16x8* __restrict__ BoL = (const bf16x8*)(ws + WOL_OFF);
    const float*  __restrict__ bg  = (const float*)(ws + BG_OFF);
    const float*  __restrict__ boP = (const float*)(ws + BO_OFF);

    const float bg0 = bg[nt0 * 32 + lm];
    const float bg1 = bg[nt1 * 32 + lm];
    const int yrt = w >> 2, yct = w & 3;          // valid for lo waves
    const float bo_v = boP[yct * 32 + lm];

    // A-fragment base byte offset: row = lm, k-half = l5*8  (rt=1 adds 16896 = 32*528)
    const int aoff = lm * (CSTRIDE * 2) + l5 * 16;
    // h-write column byte offset (cell = cb*32 + lm)
    const int colb = (cb * 32 + lm) * 2;
    float* exch = (float*)(smem + EXCH_OFF);
    const int exbase = (cb * 2 * 16) * 64 + lane;  // + rt*1024 + r*64

    // c0 = h0 (hi waves only), D-fragment register mapping
    float cst[2][16];
    if (!isLo) {
        const unsigned short* hhi = (const unsigned short*)(smem + HHI_OFF);
        const unsigned short* hlo = (const unsigned short*)(smem + HLO_OFF);
        #pragma unroll
        for (int rt = 0; rt < 2; ++rt)
            #pragma unroll
            for (int r = 0; r < 16; ++r) {
                int row = rt * 32 + (r & 3) + 8 * (r >> 2) + 4 * l5;
                int cell = cb * 32 + lm;
                cst[rt][r] = bits2f(hhi[row * CSTRIDE + cell]) + bits2f(hlo[row * CSTRIDE + cell]);
            }
    }

    for (int t = 0; t < STEPS; ++t) {
        // ---- gates GEMM: 2 column tiles x 2 row tiles, 3-term split-bf16 ----
        f32x16 g0[2], g1[2];
        g0[0] = splat16(bg0); g0[1] = splat16(bg0);
        g1[0] = splat16(bg1); g1[1] = splat16(bg1);

        #pragma unroll 2
        for (int kk = 0; kk < 16; ++kk) {
            const int kb = kk * 32;
            bf16x8 ah0 = __builtin_bit_cast(bf16x8, *(const i32x4*)(smem + HHI_OFF + aoff + kb));
            bf16x8 ah1 = __builtin_bit_cast(bf16x8, *(const i32x4*)(smem + HHI_OFF + 16896 + aoff + kb));
            bf16x8 al0 = __builtin_bit_cast(bf16x8, *(const i32x4*)(smem + HLO_OFF + aoff + kb));
            bf16x8 al1 = __builtin_bit_cast(bf16x8, *(const i32x4*)(smem + HLO_OFF + 16896 + aoff + kb));
            bf16x8 b0h = BgH[(nt0 * 16 + kk) * 64 + lane];
            bf16x8 b0l = BgL[(nt0 * 16 + kk) * 64 + lane];
            bf16x8 b1h = BgH[(nt1 * 16 + kk) * 64 + lane];
            bf16x8 b1l = BgL[(nt1 * 16 + kk) * 64 + lane];
            g0[0] = __builtin_amdgcn_mfma_f32_32x32x16_bf16(ah0, b0h, g0[0], 0, 0, 0);
            g0[1] = __builtin_amdgcn_mfma_f32_32x32x16_bf16(ah1, b0h, g0[1], 0, 0, 0);
            g0[0] = __builtin_amdgcn_mfma_f32_32x32x16_bf16(al0, b0h, g0[0], 0, 0, 0);
            g0[1] = __builtin_amdgcn_mfma_f32_32x32x16_bf16(al1, b0h, g0[1], 0, 0, 0);
            g0[0] = __builtin_amdgcn_mfma_f32_32x32x16_bf16(ah0, b0l, g0[0], 0, 0, 0);
            g0[1] = __builtin_amdgcn_mfma_f32_32x32x16_bf16(ah1, b0l, g0[1], 0, 0, 0);
            g1[0] = __builtin_amdgcn_mfma_f32_32x32x16_bf16(ah0, b1h, g1[0], 0, 0, 0);
            g1[1] = __builtin_amdgcn_mfma_f32_32x32x16_bf16(ah1, b1h, g1[1], 0, 0, 0);
            g1[0] = __builtin_amdgcn_mfma_f32_32x32x16_bf16(al0, b1h, g1[0], 0, 0, 0);
            g1[1] = __builtin_amdgcn_mfma_f32_32x32x16_bf16(al1, b1h, g1[1], 0, 0, 0);
            g1[0] = __builtin_amdgcn_mfma_f32_32x32x16_bf16(ah0, b1l, g1[0], 0, 0, 0);
            g1[1] = __builtin_amdgcn_mfma_f32_32x32x16_bf16(ah1, b1l, g1[1], 0, 0, 0);
        }

        if (isLo) {
            // p = sigmoid(i) * tanh(g) -> exchange (f32, exact)
            #pragma unroll
            for (int rt = 0; rt < 2; ++rt)
                #pragma unroll
                for (int r = 0; r < 16; ++r)
                    exch[exbase + rt * 1024 + r * 64] =
                        fast_sigmoid(g0[rt][r]) * fast_tanh(g1[rt][r]);
        }

        __syncthreads();   // A: exch ready; all gate-reads of h done

        if (!isLo) {
            // c' = sigmoid(f)*c + p ; h = sigmoid(o)*tanh(c') ; write h hi/lo
            #pragma unroll
            for (int rt = 0; rt < 2; ++rt)
                #pragma unroll
                for (int r = 0; r < 16; ++r) {
                    float vf = fast_sigmoid(g0[rt][r]);
                    float vo = fast_sigmoid(g1[rt][r]);
                    float p  = exch[exbase + rt * 1024 + r * 64];
                    float c  = fmaf(vf, cst[rt][r], p);
                    cst[rt][r] = c;
                    float h  = vo * fast_tanh(c);
                    unsigned short hb = bf16bits(h);
                    unsigned short lb = bf16bits(h - bits2f(hb));
                    int row = rt * 32 + (r & 3) + 8 * (r >> 2) + 4 * l5;
                    int ro  = row * (CSTRIDE * 2) + colb;
                    *(unsigned short*)(smem + HHI_OFF + ro) = hb;
                    *(unsigned short*)(smem + HLO_OFF + ro) = lb;
                }
        }

        __syncthreads();   // B: h_new visible

        if (isLo) {
            // y = h_new @ Wo^T + bo ; lo wave -> (rt = w>>2, ct = w&3), deduped B
            f32x16 ya = splat16(bo_v);
            const int yao = yrt * 16896 + aoff;
            #pragma unroll 2
            for (int kk = 0; kk < 16; ++kk) {
                const int kb = kk * 32;
                bf16x8 ah = __builtin_bit_cast(bf16x8, *(const i32x4*)(smem + HHI_OFF + yao + kb));
                bf16x8 al = __builtin_bit_cast(bf16x8, *(const i32x4*)(smem + HLO_OFF + yao + kb));
                bf16x8 bh = BoH[(yct * 16 + kk) * 64 + lane];
                bf16x8 bl = BoL[(yct * 16 + kk) * 64 + lane];
                ya = __builtin_amdgcn_mfma_f32_32x32x16_bf16(ah, bh, ya, 0, 0, 0);
                ya = __builtin_amdgcn_mfma_f32_32x32x16_bf16(al, bh, ya, 0, 0, 0);
                ya = __builtin_amdgcn_mfma_f32_32x32x16_bf16(ah, bl, ya, 0, 0, 0);
            }
            const int col = yct * 32 + lm;
            if (col < N_Y) {
                #pragma unroll
                for (int r = 0; r < 16; ++r) {
                    int row = yrt * 32 + (r & 3) + 8 * (r >> 2) + 4 * l5;
                    out[(size_t)(r0 + row) * (STEPS * N_Y) + t * N_Y + col] = ya[r];
                }
            }
        }
        // Race-freedom: h-write(t+1) happens only after barrier A(t+1), which lo
        // waves reach only after finishing y(t); exch(t+1) writes happen after
        // barrier B(t), while exch(t) reads happen before it.
    }
}

extern "C" void kernel_launch(void* const* d_in, const int* in_sizes, int n_in,
                              void* d_out, int out_size, void* d_ws, size_t ws_size,
                              hipStream_t stream) {
    const float* x   = (const float*)d_in[0];
    const float* W1  = (const float*)d_in[1];
    const float* b1  = (const float*)d_in[2];
    const float* W2  = (const float*)d_in[3];
    const float* b2  = (const float*)d_in[4];
    const float* W3  = (const float*)d_in[5];
    const float* b3  = (const float*)d_in[6];
    const float* Wih = (const float*)d_in[7];
    const float* Whh = (const float*)d_in[8];
    const float* bih = (const float*)d_in[9];
    const float* bhh = (const float*)d_in[10];
    const float* Wo  = (const float*)d_in[11];
    const float* bo  = (const float*)d_in[12];
    float* out = (float*)d_out;
    char* ws = (char*)d_ws;

    hipLaunchKernelGGL(prep_kernel, dim3(1157), dim3(256), 0, stream,
                       Wih, Whh, bih, bhh, Wo, bo, ws);
    hipLaunchKernelGGL(rnn_main, dim3(BATCH / ROWS), dim3(NTHR), 0, stream,
                       x, W1, b1, W2, b2, W3, b3, ws, out);
}